// Round 4
// baseline (695.676 us; speedup 1.0000x reference)
//
#include <hip/hip_runtime.h>
#include <hip/hip_bf16.h>
#include <cstddef>

#define N_NODES 20000
#define N_EDGES 320000
#define XDIM 128
#define H 256
#define LAYERS 4
#define G_GRAPHS 128
#define C_OUT 10
#define EPS_BN 1e-5f

typedef __attribute__((ext_vector_type(8))) short short8;
typedef __attribute__((ext_vector_type(4))) float f32x4;

// ---------------- degree histogram (by dst) ----------------
__global__ void hist_kernel(const int* __restrict__ dst, int* __restrict__ cnt, int E) {
    int e = blockIdx.x * blockDim.x + threadIdx.x;
    if (e < E) atomicAdd(&cnt[dst[e]], 1);
}

// ---------------- exclusive scan of cnt -> rowstart[N+1], fused dinv ----------------
__global__ void scan_kernel(const int* __restrict__ cnt, int* __restrict__ rowstart,
                            float* __restrict__ dinv, int N) {
    __shared__ int partial[1024];
    int tid = threadIdx.x;
    int chunk = (N + 1023) / 1024;
    int start = tid * chunk;
    int lsum = 0;
    for (int i = 0; i < chunk; ++i) {
        int idx = start + i;
        if (idx < N) {
            int c = cnt[idx];
            dinv[idx] = 1.0f / sqrtf((float)c + 1.0f);
            lsum += c;
        }
    }
    partial[tid] = lsum;
    __syncthreads();
    for (int off = 1; off < 1024; off <<= 1) {
        int v = (tid >= off) ? partial[tid - off] : 0;
        __syncthreads();
        partial[tid] += v;
        __syncthreads();
    }
    int run = (tid == 0) ? 0 : partial[tid - 1];
    for (int i = 0; i < chunk; ++i) {
        int idx = start + i;
        if (idx < N) { rowstart[idx] = run; run += cnt[idx]; }
    }
    if (tid == 1023) rowstart[N] = partial[1023];
}

// ---------------- CSR fill ----------------
__global__ void fill_kernel(const int* __restrict__ src, const int* __restrict__ dst,
                            const int* __restrict__ rowstart, int* __restrict__ cursor,
                            const float* __restrict__ dinv,
                            int* __restrict__ csr_src, float* __restrict__ csr_w, int E) {
    int e = blockIdx.x * blockDim.x + threadIdx.x;
    if (e < E) {
        int s = src[e], d = dst[e];
        int pos = rowstart[d] + atomicAdd(&cursor[d], 1);
        csr_src[pos] = s;
        csr_w[pos] = dinv[s] * dinv[d];
    }
}

// ---------------- fp32 -> bf16 cast ----------------
__global__ void cast_bf16_kernel(const float* __restrict__ in, __hip_bfloat16* __restrict__ out, int n) {
    int i = blockIdx.x * blockDim.x + threadIdx.x;
    if (i < n) out[i] = __float2bfloat16(in[i]);
}

// ---------------- transpose+cast ----------------
__global__ void tcast_kernel(const float* __restrict__ in, __hip_bfloat16* __restrict__ out,
                             int R, int C, int layers) {
    int i = blockIdx.x * blockDim.x + threadIdx.x;
    int per = R * C;
    if (i >= per * layers) return;
    int l = i / per, rem = i - l * per;
    int r = rem / C, c = rem - r * C;
    out[(size_t)l * per + (size_t)c * R + r] = __float2bfloat16(in[i]);
}

// ---------------- bf16 MFMA GEMM (128x128 tile, 4 waves, 16x16x32) ----------------
template <int K>
__global__ __launch_bounds__(256) void gemm_bf16_kernel(
    const __hip_bfloat16* __restrict__ A,   // [M,K] row-major
    const __hip_bfloat16* __restrict__ BT,  // [Nn,K] row-major (B transposed)
    const float* __restrict__ bias,         // [Nn] or nullptr
    __hip_bfloat16* __restrict__ Cbf,       // [M,Nn]
    int M, int Nn) {
    __shared__ short As[128 * 32];
    __shared__ short Bs[128 * 32];
    const short* Ash = (const short*)A;
    const short* Bsh = (const short*)BT;
    int tid = threadIdx.x;
    int lane = tid & 63;
    int wave = tid >> 6;
    int quad = lane >> 4;
    int lr = lane & 15;
    int wm = (wave & 1) * 64;
    int wn = (wave >> 1) * 64;
    int Mblk = blockIdx.x * 128;
    int Nblk = blockIdx.y * 128;

    f32x4 acc[4][4];
#pragma unroll
    for (int i = 0; i < 4; ++i)
#pragma unroll
        for (int j = 0; j < 4; ++j) acc[i][j] = (f32x4){0.f, 0.f, 0.f, 0.f};

    for (int k0 = 0; k0 < K; k0 += 32) {
#pragma unroll
        for (int i = 0; i < 2; ++i) {
            int s = i * 256 + tid;
            int row = s >> 2;
            int qs = s & 3;
            int qg = qs ^ ((row >> 1) & 3);
            int arow = Mblk + row; if (arow >= M) arow = M - 1;
            *(float4*)&As[row * 32 + qs * 8] =
                *(const float4*)(Ash + (size_t)arow * K + k0 + qg * 8);
            int brow = Nblk + row;
            *(float4*)&Bs[row * 32 + qs * 8] =
                *(const float4*)(Bsh + (size_t)brow * K + k0 + qg * 8);
        }
        __syncthreads();
        short8 af[4], bfr[4];
#pragma unroll
        for (int mi = 0; mi < 4; ++mi) {
            int r = wm + mi * 16 + lr;
            af[mi] = *(const short8*)&As[r * 32 + (quad ^ ((r >> 1) & 3)) * 8];
        }
#pragma unroll
        for (int ni = 0; ni < 4; ++ni) {
            int r = wn + ni * 16 + lr;
            bfr[ni] = *(const short8*)&Bs[r * 32 + (quad ^ ((r >> 1) & 3)) * 8];
        }
#pragma unroll
        for (int mi = 0; mi < 4; ++mi)
#pragma unroll
            for (int ni = 0; ni < 4; ++ni)
                acc[mi][ni] = __builtin_amdgcn_mfma_f32_16x16x32_bf16(af[mi], bfr[ni], acc[mi][ni], 0, 0, 0);
        __syncthreads();
    }
#pragma unroll
    for (int mi = 0; mi < 4; ++mi) {
#pragma unroll
        for (int r = 0; r < 4; ++r) {
            int m = Mblk + wm + mi * 16 + quad * 4 + r;
            if (m < M) {
#pragma unroll
                for (int ni = 0; ni < 4; ++ni) {
                    int n = Nblk + wn + ni * 16 + lr;
                    float v = acc[mi][ni][r];
                    if (bias) v += bias[n];
                    Cbf[(size_t)m * Nn + n] = __float2bfloat16(v);
                }
            }
        }
    }
}

// ---------------- aggregation, channel-quartered for L2 residency -----------------
// quarter = blockIdx & 3 (XCD-affine under %8 round-robin dispatch). Each wave
// handles one node; half-waves process two edges simultaneously (4B bf16x2 loads).
__global__ __launch_bounds__(256) void agg_kernel(const __hip_bfloat16* __restrict__ t,
                           const int* __restrict__ rowstart,
                           const int* __restrict__ csr_src,
                           const float* __restrict__ csr_w,
                           const float* __restrict__ dinv,
                           const float* __restrict__ convB,
                           float* __restrict__ out, int N) {
    int q = blockIdx.x & 3;
    int grp = blockIdx.x >> 2;
    int wave = threadIdx.x >> 6;
    int lane = threadIdx.x & 63;
    int sub = lane >> 5;       // which edge of the pair
    int cp = lane & 31;        // channel-pair within quarter
    int n = grp * 4 + wave;
    if (n >= N) return;
    int c0 = q * 64 + cp * 2;
    const ushort* tp = (const ushort*)t;
    int s = rowstart[n], e = rowstart[n + 1];
    float a0 = 0.f, a1 = 0.f;
    for (int i = s; i < e; i += 2) {
        int j = i + sub;
        float w = 0.f;
        int idx = n;
        if (j < e) { idx = csr_src[j]; w = csr_w[j]; }
        unsigned v = *(const unsigned*)(tp + (size_t)idx * H + c0);
        a0 += __uint_as_float(v << 16) * w;
        a1 += __uint_as_float(v & 0xffff0000u) * w;
    }
    if (sub == 0) {
        float dn = dinv[n];
        float w = dn * dn;
        unsigned v = *(const unsigned*)(tp + (size_t)n * H + c0);
        a0 += __uint_as_float(v << 16) * w;
        a1 += __uint_as_float(v & 0xffff0000u) * w;
    }
    a0 += __shfl_down(a0, 32);
    a1 += __shfl_down(a1, 32);
    if (sub == 0) {
        float2 o;
        o.x = a0 + convB[c0];
        o.y = a1 + convB[c0 + 1];
        *(float2*)(out + (size_t)n * H + c0) = o;
    }
}

// ---------------- per-channel sums / sumsq over [N,H] ----------------
__global__ void stats_kernel(const float* __restrict__ t, float* __restrict__ stats, int N) {
    int c = threadIdx.x;  // H
    float s = 0.f, s2 = 0.f;
    for (int r = blockIdx.x; r < N; r += gridDim.x) {
        float v = t[(size_t)r * H + c];
        s += v;
        s2 += v * v;
    }
    atomicAdd(&stats[c], s);
    atomicAdd(&stats[H + c], s2);
}

// ---------------- BN (batch stats) + ReLU -> bf16 ----------------
__global__ void bnrelu_kernel(const float* __restrict__ t, const float* __restrict__ stats,
                              const float* __restrict__ gamma, const float* __restrict__ beta,
                              __hip_bfloat16* __restrict__ out, int N) {
    int c = threadIdx.x;  // H
    float invN = 1.0f / (float)N;
    float mean = stats[c] * invN;
    float var = stats[H + c] * invN - mean * mean;
    float sc = gamma[c] / sqrtf(var + EPS_BN);
    float sh = beta[c] - mean * sc;
    for (int r = blockIdx.x; r < N; r += gridDim.x) {
        float v = t[(size_t)r * H + c];
        out[(size_t)r * H + c] = __float2bfloat16(fmaxf(v * sc + sh, 0.f));
    }
}

// ---------------- global mean pool (batch sorted), 2 channels/thread ----------------
__global__ void pool_kernel(const __hip_bfloat16* __restrict__ h, const int* __restrict__ batch,
                            float* __restrict__ g, int N) {
    int gid = blockIdx.x;
    int lo = 0, hi = N;
    while (lo < hi) { int mid = (lo + hi) >> 1; if (batch[mid] < gid) lo = mid + 1; else hi = mid; }
    int s = lo;
    lo = s; hi = N;
    while (lo < hi) { int mid = (lo + hi) >> 1; if (batch[mid] < gid + 1) lo = mid + 1; else hi = mid; }
    int e = lo;
    int c = threadIdx.x;  // 128 threads, 2 channels each
    const ushort* hp = (const ushort*)h;
    float a0 = 0.f, a1 = 0.f;
    for (int r = s; r < e; ++r) {
        unsigned v = *(const unsigned*)(hp + (size_t)r * H + c * 2);
        a0 += __uint_as_float(v << 16);
        a1 += __uint_as_float(v & 0xffff0000u);
    }
    float inv = 1.0f / fmaxf((float)(e - s), 1.0f);
    float2 o; o.x = a0 * inv; o.y = a1 * inv;
    *(float2*)(g + (size_t)gid * H + c * 2) = o;
}

// ---------------- FC with compile-time K/NN ----------------
template <int K, int NN>
__global__ __launch_bounds__(256) void fc_lds_kernel(const float* __restrict__ in,
                                                     const float* __restrict__ W,
                                                     const float* __restrict__ b,
                                                     float* __restrict__ out) {
    __shared__ float row[K];
    int g = blockIdx.x;
    for (int k = threadIdx.x; k < K; k += 256) row[k] = in[(size_t)g * K + k];
    __syncthreads();
    int hc = threadIdx.x;
    if (hc < NN) {
        float acc = b[hc];
#pragma unroll
        for (int k = 0; k < K; ++k) acc += row[k] * W[k * NN + hc];
        out[(size_t)g * NN + hc] = acc;
    }
}

// ---------------- final FC ----------------
__global__ void fc_out_kernel(const float* __restrict__ in, const float* __restrict__ W,
                              const float* __restrict__ b, float* __restrict__ out) {
    int t = blockIdx.x * blockDim.x + threadIdx.x;
    if (t >= G_GRAPHS * C_OUT) return;
    int g = t / C_OUT, c = t % C_OUT;
    float acc = b[c];
#pragma unroll 16
    for (int k = 0; k < H; ++k) acc += in[(size_t)g * H + k] * W[k * C_OUT + c];
    out[t] = acc;
}

// ---------------- BN over small [G,H] ----------------
__global__ void bn_head_kernel(const float* __restrict__ in, const float* __restrict__ gamma,
                               const float* __restrict__ beta, float* __restrict__ out,
                               int Grows, int relu) {
    int c = blockIdx.x;
    int r = threadIdx.x;
    __shared__ float red[G_GRAPHS];
    float v = in[r * H + c];
    red[r] = v;
    __syncthreads();
    for (int off = G_GRAPHS / 2; off > 0; off >>= 1) {
        if (r < off) red[r] += red[r + off];
        __syncthreads();
    }
    float mean = red[0] / (float)Grows;
    __syncthreads();
    float d = v - mean;
    red[r] = d * d;
    __syncthreads();
    for (int off = G_GRAPHS / 2; off > 0; off >>= 1) {
        if (r < off) red[r] += red[r + off];
        __syncthreads();
    }
    float var = red[0] / (float)Grows;
    float y = gamma[c] * d / sqrtf(var + EPS_BN) + beta[c];
    if (relu) y = fmaxf(y, 0.f);
    out[r * H + c] = y;
}

extern "C" void kernel_launch(void* const* d_in, const int* in_sizes, int n_in,
                              void* d_out, int out_size, void* d_ws, size_t ws_size,
                              hipStream_t stream) {
    const float* x     = (const float*)d_in[0];
    const int*   edge  = (const int*)d_in[1];
    const int*   batch = (const int*)d_in[2];
    const float* encW  = (const float*)d_in[3];
    const float* encB  = (const float*)d_in[4];
    const float* convW = (const float*)d_in[5];
    const float* convB = (const float*)d_in[6];
    const float* bnG   = (const float*)d_in[7];
    const float* bnB   = (const float*)d_in[8];
    const float* fcW1  = (const float*)d_in[9];
    const float* fcB1  = (const float*)d_in[10];
    const float* fcG1  = (const float*)d_in[11];
    const float* fcBe1 = (const float*)d_in[12];
    const float* fcW2  = (const float*)d_in[13];
    const float* fcB2  = (const float*)d_in[14];
    const float* fcG2  = (const float*)d_in[15];
    const float* fcBe2 = (const float*)d_in[16];
    const float* fcW3  = (const float*)d_in[17];
    const float* fcB3  = (const float*)d_in[18];
    float* out = (float*)d_out;

    const int* srcIdx = edge;
    const int* dstIdx = edge + N_EDGES;

    char* base = (char*)d_ws;
    size_t off = 0;
    auto alloc = [&](size_t bytes) -> void* {
        void* p = base + off;
        off = (off + bytes + 255) & ~(size_t)255;
        return p;
    };
    int*   cnt      = (int*)alloc(N_NODES * 4);
    int*   cursor   = (int*)alloc(N_NODES * 4);
    int*   rowstart = (int*)alloc((N_NODES + 1) * 4);
    float* dinv     = (float*)alloc(N_NODES * 4);
    int*   csr_src  = (int*)alloc(N_EDGES * 4);
    float* csr_w    = (float*)alloc(N_EDGES * 4);
    float* bnstats  = (float*)alloc(LAYERS * 2 * H * 4);
    __hip_bfloat16* xbf    = (__hip_bfloat16*)alloc((size_t)N_NODES * XDIM * 2);
    __hip_bfloat16* encWT  = (__hip_bfloat16*)alloc((size_t)H * XDIM * 2);
    __hip_bfloat16* convWT = (__hip_bfloat16*)alloc((size_t)LAYERS * H * H * 2);
    __hip_bfloat16* hbf    = (__hip_bfloat16*)alloc((size_t)N_NODES * H * 2);
    __hip_bfloat16* tbf    = (__hip_bfloat16*)alloc((size_t)N_NODES * H * 2);
    float* t2buf = (float*)alloc((size_t)N_NODES * H * 4);
    float* gpool = (float*)alloc(G_GRAPHS * H * 4);
    float* m1    = (float*)alloc(G_GRAPHS * H * 4);
    float* m2    = (float*)alloc(G_GRAPHS * H * 4);

    hipMemsetAsync(cnt, 0, N_NODES * 4, stream);
    hipMemsetAsync(cursor, 0, N_NODES * 4, stream);
    hipMemsetAsync(bnstats, 0, LAYERS * 2 * H * 4, stream);

    // CSR build
    hist_kernel<<<(N_EDGES + 255) / 256, 256, 0, stream>>>(dstIdx, cnt, N_EDGES);
    scan_kernel<<<1, 1024, 0, stream>>>(cnt, rowstart, dinv, N_NODES);
    fill_kernel<<<(N_EDGES + 255) / 256, 256, 0, stream>>>(srcIdx, dstIdx, rowstart, cursor,
                                                           dinv, csr_src, csr_w, N_EDGES);

    // casts
    cast_bf16_kernel<<<(N_NODES * XDIM + 255) / 256, 256, 0, stream>>>(x, xbf, N_NODES * XDIM);
    tcast_kernel<<<(XDIM * H + 255) / 256, 256, 0, stream>>>(encW, encWT, XDIM, H, 1);
    tcast_kernel<<<(LAYERS * H * H + 255) / 256, 256, 0, stream>>>(convW, convWT, H, H, LAYERS);

    // encoder
    dim3 gridG((N_NODES + 127) / 128, H / 128);
    gemm_bf16_kernel<XDIM><<<gridG, 256, 0, stream>>>(xbf, encWT, encB, hbf, N_NODES, H);

    // conv layers
    for (int l = 0; l < LAYERS; ++l) {
        gemm_bf16_kernel<H><<<gridG, 256, 0, stream>>>(hbf, convWT + (size_t)l * H * H, nullptr,
                                                       tbf, N_NODES, H);
        agg_kernel<<<(N_NODES / 4) * 4, 256, 0, stream>>>(tbf, rowstart, csr_src, csr_w, dinv,
                                                          convB + l * H, t2buf, N_NODES);
        stats_kernel<<<256, H, 0, stream>>>(t2buf, bnstats + l * 2 * H, N_NODES);
        bnrelu_kernel<<<512, H, 0, stream>>>(t2buf, bnstats + l * 2 * H,
                                             bnG + l * H, bnB + l * H, hbf, N_NODES);
    }

    // pool
    pool_kernel<<<G_GRAPHS, 128, 0, stream>>>(hbf, batch, gpool, N_NODES);

    // head
    fc_lds_kernel<H, H><<<G_GRAPHS, 256, 0, stream>>>(gpool, fcW1, fcB1, m1);
    bn_head_kernel<<<H, G_GRAPHS, 0, stream>>>(m1, fcG1, fcBe1, m1, G_GRAPHS, 1);
    fc_lds_kernel<H, H><<<G_GRAPHS, 256, 0, stream>>>(m1, fcW2, fcB2, m2);
    bn_head_kernel<<<H, G_GRAPHS, 0, stream>>>(m2, fcG2, fcBe2, m2, G_GRAPHS, 0);
    fc_out_kernel<<<(G_GRAPHS * C_OUT + 255) / 256, 256, 0, stream>>>(m2, fcW3, fcB3, out);
}

// Round 5
// 538.367 us; speedup vs baseline: 1.2922x; 1.2922x over previous
//
#include <hip/hip_runtime.h>
#include <hip/hip_bf16.h>
#include <cstddef>

#define N_NODES 20000
#define N_EDGES 320000
#define XDIM 128
#define H 256
#define LAYERS 4
#define G_GRAPHS 128
#define C_OUT 10
#define EPS_BN 1e-5f
#define NSLOT 64          // stats partial slots (contention = N/64 per address)

typedef __attribute__((ext_vector_type(8))) short short8;
typedef __attribute__((ext_vector_type(4))) float f32x4;

// ---------------- degree histogram (by dst) ----------------
__global__ void hist_kernel(const int* __restrict__ dst, int* __restrict__ cnt, int E) {
    int e = blockIdx.x * blockDim.x + threadIdx.x;
    if (e < E) atomicAdd(&cnt[dst[e]], 1);
}

// ---------------- exclusive scan of cnt -> rowstart[N+1], fused dinv ----------------
__global__ void scan_kernel(const int* __restrict__ cnt, int* __restrict__ rowstart,
                            float* __restrict__ dinv, int N) {
    __shared__ int partial[1024];
    int tid = threadIdx.x;
    int chunk = (N + 1023) / 1024;
    int start = tid * chunk;
    int lsum = 0;
    for (int i = 0; i < chunk; ++i) {
        int idx = start + i;
        if (idx < N) {
            int c = cnt[idx];
            dinv[idx] = 1.0f / sqrtf((float)c + 1.0f);
            lsum += c;
        }
    }
    partial[tid] = lsum;
    __syncthreads();
    for (int off = 1; off < 1024; off <<= 1) {
        int v = (tid >= off) ? partial[tid - off] : 0;
        __syncthreads();
        partial[tid] += v;
        __syncthreads();
    }
    int run = (tid == 0) ? 0 : partial[tid - 1];
    for (int i = 0; i < chunk; ++i) {
        int idx = start + i;
        if (idx < N) { rowstart[idx] = run; run += cnt[idx]; }
    }
    if (tid == 1023) rowstart[N] = partial[1023];
}

// ---------------- CSR fill ----------------
__global__ void fill_kernel(const int* __restrict__ src, const int* __restrict__ dst,
                            const int* __restrict__ rowstart, int* __restrict__ cursor,
                            const float* __restrict__ dinv,
                            int* __restrict__ csr_src, float* __restrict__ csr_w, int E) {
    int e = blockIdx.x * blockDim.x + threadIdx.x;
    if (e < E) {
        int s = src[e], d = dst[e];
        int pos = rowstart[d] + atomicAdd(&cursor[d], 1);
        csr_src[pos] = s;
        csr_w[pos] = dinv[s] * dinv[d];
    }
}

// ---------------- fp32 -> bf16 cast ----------------
__global__ void cast_bf16_kernel(const float* __restrict__ in, __hip_bfloat16* __restrict__ out, int n) {
    int i = blockIdx.x * blockDim.x + threadIdx.x;
    if (i < n) out[i] = __float2bfloat16(in[i]);
}

// ---------------- transpose+cast ----------------
__global__ void tcast_kernel(const float* __restrict__ in, __hip_bfloat16* __restrict__ out,
                             int R, int C, int layers) {
    int i = blockIdx.x * blockDim.x + threadIdx.x;
    int per = R * C;
    if (i >= per * layers) return;
    int l = i / per, rem = i - l * per;
    int r = rem / C, c = rem - r * C;
    out[(size_t)l * per + (size_t)c * R + r] = __float2bfloat16(in[i]);
}

// ---------------- bf16 MFMA GEMM (128x128 tile, 4 waves, 16x16x32) ----------------
template <int K>
__global__ __launch_bounds__(256) void gemm_bf16_kernel(
    const __hip_bfloat16* __restrict__ A,   // [M,K] row-major
    const __hip_bfloat16* __restrict__ BT,  // [Nn,K] row-major (B transposed)
    const float* __restrict__ bias,         // [Nn] or nullptr
    __hip_bfloat16* __restrict__ Cbf,       // [M,Nn]
    int M, int Nn) {
    __shared__ short As[128 * 32];
    __shared__ short Bs[128 * 32];
    const short* Ash = (const short*)A;
    const short* Bsh = (const short*)BT;
    int tid = threadIdx.x;
    int lane = tid & 63;
    int wave = tid >> 6;
    int quad = lane >> 4;
    int lr = lane & 15;
    int wm = (wave & 1) * 64;
    int wn = (wave >> 1) * 64;
    int Mblk = blockIdx.x * 128;
    int Nblk = blockIdx.y * 128;

    f32x4 acc[4][4];
#pragma unroll
    for (int i = 0; i < 4; ++i)
#pragma unroll
        for (int j = 0; j < 4; ++j) acc[i][j] = (f32x4){0.f, 0.f, 0.f, 0.f};

    for (int k0 = 0; k0 < K; k0 += 32) {
#pragma unroll
        for (int i = 0; i < 2; ++i) {
            int s = i * 256 + tid;
            int row = s >> 2;
            int qs = s & 3;
            int qg = qs ^ ((row >> 1) & 3);
            int arow = Mblk + row; if (arow >= M) arow = M - 1;
            *(float4*)&As[row * 32 + qs * 8] =
                *(const float4*)(Ash + (size_t)arow * K + k0 + qg * 8);
            int brow = Nblk + row;
            *(float4*)&Bs[row * 32 + qs * 8] =
                *(const float4*)(Bsh + (size_t)brow * K + k0 + qg * 8);
        }
        __syncthreads();
        short8 af[4], bfr[4];
#pragma unroll
        for (int mi = 0; mi < 4; ++mi) {
            int r = wm + mi * 16 + lr;
            af[mi] = *(const short8*)&As[r * 32 + (quad ^ ((r >> 1) & 3)) * 8];
        }
#pragma unroll
        for (int ni = 0; ni < 4; ++ni) {
            int r = wn + ni * 16 + lr;
            bfr[ni] = *(const short8*)&Bs[r * 32 + (quad ^ ((r >> 1) & 3)) * 8];
        }
#pragma unroll
        for (int mi = 0; mi < 4; ++mi)
#pragma unroll
            for (int ni = 0; ni < 4; ++ni)
                acc[mi][ni] = __builtin_amdgcn_mfma_f32_16x16x32_bf16(af[mi], bfr[ni], acc[mi][ni], 0, 0, 0);
        __syncthreads();
    }
#pragma unroll
    for (int mi = 0; mi < 4; ++mi) {
#pragma unroll
        for (int r = 0; r < 4; ++r) {
            int m = Mblk + wm + mi * 16 + quad * 4 + r;
            if (m < M) {
#pragma unroll
                for (int ni = 0; ni < 4; ++ni) {
                    int n = Nblk + wn + ni * 16 + lr;
                    float v = acc[mi][ni][r];
                    if (bias) v += bias[n];
                    Cbf[(size_t)m * Nn + n] = __float2bfloat16(v);
                }
            }
        }
    }
}

// ---------------- aggregation + fused BN-stats partials -----------------
// Block = one node, 4 waves. Each wave gathers a FULL 512B row per load
// (8B/lane = 4 channels), waves split the edge list, unroll x4 ->
// 16 independent gathers in flight per block. LDS combine, then per-block
// stats atomics into 64-slot partial buffer (contention N/64 per address).
__global__ __launch_bounds__(256) void agg_kernel(const __hip_bfloat16* __restrict__ t,
                           const int* __restrict__ rowstart,
                           const int* __restrict__ csr_src,
                           const float* __restrict__ csr_w,
                           const float* __restrict__ dinv,
                           const float* __restrict__ convB,
                           float* __restrict__ out,
                           float* __restrict__ spart,  // [NSLOT][2*H]
                           int N) {
    __shared__ float4 red[4][64];
    int n = blockIdx.x;
    int wave = threadIdx.x >> 6;
    int lane = threadIdx.x & 63;
    int s = rowstart[n], e = rowstart[n + 1];
    const ushort* tp = (const ushort*)t;
    float a0 = 0.f, a1 = 0.f, a2 = 0.f, a3 = 0.f;
    for (int j0 = s + wave; j0 < e; j0 += 16) {
#pragma unroll
        for (int u = 0; u < 4; ++u) {
            int j = j0 + u * 4;
            int idx = n; float w = 0.f;
            if (j < e) { idx = csr_src[j]; w = csr_w[j]; }
            uint2 v = *(const uint2*)(tp + (size_t)idx * H + lane * 4);
            a0 += __uint_as_float(v.x << 16) * w;
            a1 += __uint_as_float(v.x & 0xffff0000u) * w;
            a2 += __uint_as_float(v.y << 16) * w;
            a3 += __uint_as_float(v.y & 0xffff0000u) * w;
        }
    }
    red[wave][lane] = make_float4(a0, a1, a2, a3);
    __syncthreads();
    int c = threadIdx.x;  // channel
    const float* rf = (const float*)red;
    float val = rf[c] + rf[256 + c] + rf[512 + c] + rf[768 + c];
    float dn = dinv[n];
    unsigned sv = tp[(size_t)n * H + c];
    val += __uint_as_float(sv << 16) * (dn * dn) + convB[c];
    out[(size_t)n * H + c] = val;
    float* sp = spart + (size_t)(n & (NSLOT - 1)) * (2 * H);
    atomicAdd(&sp[c], val);
    atomicAdd(&sp[H + c], val * val);
}

// ---------------- reduce stats partials: [NSLOT][2H] -> [2H] ----------------
__global__ void reduce_stats_kernel(const float* __restrict__ spart, float* __restrict__ stats) {
    int c = blockIdx.x * 256 + threadIdx.x;  // 0..511
    float s = 0.f;
#pragma unroll 8
    for (int i = 0; i < NSLOT; ++i) s += spart[(size_t)i * (2 * H) + c];
    stats[c] = s;
}

// ---------------- BN (batch stats) + ReLU -> bf16 ----------------
__global__ void bnrelu_kernel(const float* __restrict__ t, const float* __restrict__ stats,
                              const float* __restrict__ gamma, const float* __restrict__ beta,
                              __hip_bfloat16* __restrict__ out, int N) {
    int c = threadIdx.x;  // H
    float invN = 1.0f / (float)N;
    float mean = stats[c] * invN;
    float var = stats[H + c] * invN - mean * mean;
    float sc = gamma[c] / sqrtf(var + EPS_BN);
    float sh = beta[c] - mean * sc;
    for (int r = blockIdx.x; r < N; r += gridDim.x) {
        float v = t[(size_t)r * H + c];
        out[(size_t)r * H + c] = __float2bfloat16(fmaxf(v * sc + sh, 0.f));
    }
}

// ---------------- global mean pool (batch sorted), full-row-per-wave ----------------
__global__ __launch_bounds__(256) void pool_kernel(const __hip_bfloat16* __restrict__ h,
                            const int* __restrict__ batch,
                            float* __restrict__ g, int N) {
    __shared__ float4 red[4][64];
    int gid = blockIdx.x;
    int lo = 0, hi = N;
    while (lo < hi) { int mid = (lo + hi) >> 1; if (batch[mid] < gid) lo = mid + 1; else hi = mid; }
    int s = lo;
    lo = s; hi = N;
    while (lo < hi) { int mid = (lo + hi) >> 1; if (batch[mid] < gid + 1) lo = mid + 1; else hi = mid; }
    int e = lo;
    int wave = threadIdx.x >> 6;
    int lane = threadIdx.x & 63;
    const ushort* hp = (const ushort*)h;
    float a0 = 0.f, a1 = 0.f, a2 = 0.f, a3 = 0.f;
    for (int r = s + wave; r < e; r += 4) {
        uint2 v = *(const uint2*)(hp + (size_t)r * H + lane * 4);
        a0 += __uint_as_float(v.x << 16);
        a1 += __uint_as_float(v.x & 0xffff0000u);
        a2 += __uint_as_float(v.y << 16);
        a3 += __uint_as_float(v.y & 0xffff0000u);
    }
    red[wave][lane] = make_float4(a0, a1, a2, a3);
    __syncthreads();
    int c = threadIdx.x;
    const float* rf = (const float*)red;
    float sum = rf[c] + rf[256 + c] + rf[512 + c] + rf[768 + c];
    g[(size_t)gid * H + c] = sum / fmaxf((float)(e - s), 1.0f);
}

// ---------------- FC with compile-time K/NN ----------------
template <int K, int NN>
__global__ __launch_bounds__(256) void fc_lds_kernel(const float* __restrict__ in,
                                                     const float* __restrict__ W,
                                                     const float* __restrict__ b,
                                                     float* __restrict__ out) {
    __shared__ float row[K];
    int g = blockIdx.x;
    for (int k = threadIdx.x; k < K; k += 256) row[k] = in[(size_t)g * K + k];
    __syncthreads();
    int hc = threadIdx.x;
    if (hc < NN) {
        float acc = b[hc];
#pragma unroll
        for (int k = 0; k < K; ++k) acc += row[k] * W[k * NN + hc];
        out[(size_t)g * NN + hc] = acc;
    }
}

// ---------------- final FC ----------------
__global__ void fc_out_kernel(const float* __restrict__ in, const float* __restrict__ W,
                              const float* __restrict__ b, float* __restrict__ out) {
    int t = blockIdx.x * blockDim.x + threadIdx.x;
    if (t >= G_GRAPHS * C_OUT) return;
    int g = t / C_OUT, c = t % C_OUT;
    float acc = b[c];
#pragma unroll 16
    for (int k = 0; k < H; ++k) acc += in[(size_t)g * H + k] * W[k * C_OUT + c];
    out[t] = acc;
}

// ---------------- BN over small [G,H] ----------------
__global__ void bn_head_kernel(const float* __restrict__ in, const float* __restrict__ gamma,
                               const float* __restrict__ beta, float* __restrict__ out,
                               int Grows, int relu) {
    int c = blockIdx.x;
    int r = threadIdx.x;
    __shared__ float red[G_GRAPHS];
    float v = in[r * H + c];
    red[r] = v;
    __syncthreads();
    for (int off = G_GRAPHS / 2; off > 0; off >>= 1) {
        if (r < off) red[r] += red[r + off];
        __syncthreads();
    }
    float mean = red[0] / (float)Grows;
    __syncthreads();
    float d = v - mean;
    red[r] = d * d;
    __syncthreads();
    for (int off = G_GRAPHS / 2; off > 0; off >>= 1) {
        if (r < off) red[r] += red[r + off];
        __syncthreads();
    }
    float var = red[0] / (float)Grows;
    float y = gamma[c] * d / sqrtf(var + EPS_BN) + beta[c];
    if (relu) y = fmaxf(y, 0.f);
    out[r * H + c] = y;
}

extern "C" void kernel_launch(void* const* d_in, const int* in_sizes, int n_in,
                              void* d_out, int out_size, void* d_ws, size_t ws_size,
                              hipStream_t stream) {
    const float* x     = (const float*)d_in[0];
    const int*   edge  = (const int*)d_in[1];
    const int*   batch = (const int*)d_in[2];
    const float* encW  = (const float*)d_in[3];
    const float* encB  = (const float*)d_in[4];
    const float* convW = (const float*)d_in[5];
    const float* convB = (const float*)d_in[6];
    const float* bnG   = (const float*)d_in[7];
    const float* bnB   = (const float*)d_in[8];
    const float* fcW1  = (const float*)d_in[9];
    const float* fcB1  = (const float*)d_in[10];
    const float* fcG1  = (const float*)d_in[11];
    const float* fcBe1 = (const float*)d_in[12];
    const float* fcW2  = (const float*)d_in[13];
    const float* fcB2  = (const float*)d_in[14];
    const float* fcG2  = (const float*)d_in[15];
    const float* fcBe2 = (const float*)d_in[16];
    const float* fcW3  = (const float*)d_in[17];
    const float* fcB3  = (const float*)d_in[18];
    float* out = (float*)d_out;

    const int* srcIdx = edge;
    const int* dstIdx = edge + N_EDGES;

    char* base = (char*)d_ws;
    size_t off = 0;
    auto alloc = [&](size_t bytes) -> void* {
        void* p = base + off;
        off = (off + bytes + 255) & ~(size_t)255;
        return p;
    };
    int*   cnt      = (int*)alloc(N_NODES * 4);
    int*   cursor   = (int*)alloc(N_NODES * 4);
    int*   rowstart = (int*)alloc((N_NODES + 1) * 4);
    float* dinv     = (float*)alloc(N_NODES * 4);
    int*   csr_src  = (int*)alloc(N_EDGES * 4);
    float* csr_w    = (float*)alloc(N_EDGES * 4);
    float* bnstats  = (float*)alloc(LAYERS * 2 * H * 4);
    float* spart    = (float*)alloc((size_t)LAYERS * NSLOT * 2 * H * 4);  // 512 KB
    __hip_bfloat16* xbf    = (__hip_bfloat16*)alloc((size_t)N_NODES * XDIM * 2);
    __hip_bfloat16* encWT  = (__hip_bfloat16*)alloc((size_t)H * XDIM * 2);
    __hip_bfloat16* convWT = (__hip_bfloat16*)alloc((size_t)LAYERS * H * H * 2);
    __hip_bfloat16* hbf    = (__hip_bfloat16*)alloc((size_t)N_NODES * H * 2);
    __hip_bfloat16* tbf    = (__hip_bfloat16*)alloc((size_t)N_NODES * H * 2);
    float* t2buf = (float*)alloc((size_t)N_NODES * H * 4);
    float* gpool = (float*)alloc(G_GRAPHS * H * 4);
    float* m1    = (float*)alloc(G_GRAPHS * H * 4);
    float* m2    = (float*)alloc(G_GRAPHS * H * 4);

    hipMemsetAsync(cnt, 0, N_NODES * 4, stream);
    hipMemsetAsync(cursor, 0, N_NODES * 4, stream);
    hipMemsetAsync(spart, 0, (size_t)LAYERS * NSLOT * 2 * H * 4, stream);

    // CSR build
    hist_kernel<<<(N_EDGES + 255) / 256, 256, 0, stream>>>(dstIdx, cnt, N_EDGES);
    scan_kernel<<<1, 1024, 0, stream>>>(cnt, rowstart, dinv, N_NODES);
    fill_kernel<<<(N_EDGES + 255) / 256, 256, 0, stream>>>(srcIdx, dstIdx, rowstart, cursor,
                                                           dinv, csr_src, csr_w, N_EDGES);

    // casts
    cast_bf16_kernel<<<(N_NODES * XDIM + 255) / 256, 256, 0, stream>>>(x, xbf, N_NODES * XDIM);
    tcast_kernel<<<(XDIM * H + 255) / 256, 256, 0, stream>>>(encW, encWT, XDIM, H, 1);
    tcast_kernel<<<(LAYERS * H * H + 255) / 256, 256, 0, stream>>>(convW, convWT, H, H, LAYERS);

    // encoder
    dim3 gridG((N_NODES + 127) / 128, H / 128);
    gemm_bf16_kernel<XDIM><<<gridG, 256, 0, stream>>>(xbf, encWT, encB, hbf, N_NODES, H);

    // conv layers
    for (int l = 0; l < LAYERS; ++l) {
        float* spartL = spart + (size_t)l * NSLOT * 2 * H;
        gemm_bf16_kernel<H><<<gridG, 256, 0, stream>>>(hbf, convWT + (size_t)l * H * H, nullptr,
                                                       tbf, N_NODES, H);
        agg_kernel<<<N_NODES, 256, 0, stream>>>(tbf, rowstart, csr_src, csr_w, dinv,
                                                convB + l * H, t2buf, spartL, N_NODES);
        reduce_stats_kernel<<<2, 256, 0, stream>>>(spartL, bnstats + l * 2 * H);
        bnrelu_kernel<<<512, H, 0, stream>>>(t2buf, bnstats + l * 2 * H,
                                             bnG + l * H, bnB + l * H, hbf, N_NODES);
    }

    // pool
    pool_kernel<<<G_GRAPHS, 256, 0, stream>>>(hbf, batch, gpool, N_NODES);

    // head
    fc_lds_kernel<H, H><<<G_GRAPHS, 256, 0, stream>>>(gpool, fcW1, fcB1, m1);
    bn_head_kernel<<<H, G_GRAPHS, 0, stream>>>(m1, fcG1, fcBe1, m1, G_GRAPHS, 1);
    fc_lds_kernel<H, H><<<G_GRAPHS, 256, 0, stream>>>(m1, fcW2, fcB2, m2);
    bn_head_kernel<<<H, G_GRAPHS, 0, stream>>>(m2, fcG2, fcBe2, m2, G_GRAPHS, 0);
    fc_out_kernel<<<(G_GRAPHS * C_OUT + 255) / 256, 256, 0, stream>>>(m2, fcW3, fcB3, out);
}